// Round 12
// baseline (187.586 us; speedup 1.0000x reference)
//
#include <hip/hip_runtime.h>
#include <hip/hip_bf16.h>
#include <stdint.h>

typedef __hip_bfloat16 bf16;
typedef __attribute__((ext_vector_type(8))) short short8;
typedef __attribute__((ext_vector_type(4))) short s16x4;
typedef __attribute__((ext_vector_type(4))) float floatx4;

#define MFMA16(a, b, c) __builtin_amdgcn_mfma_f32_16x16x32_bf16(a, b, c, 0, 0, 0)
// s_waitcnt imm: vmcnt[3:0], expcnt[6:4]=7 (no wait), lgkmcnt[11:8]=15 (no wait)
#define WAIT_VM6 3958  // 6 | (7<<4) | (15<<8)
#define WAIT_VM4 3956  // 4 | (7<<4) | (15<<8)
#define WAIT_VM0 3952  // 0 | (7<<4) | (15<<8)

__device__ __forceinline__ void async_lds16(const void* g, void* l) {
  __builtin_amdgcn_global_load_lds((__attribute__((address_space(1))) const void*)g,
                                   (__attribute__((address_space(3))) void*)l, 16, 0, 0);
}

// RNE-round two non-NaN floats to bf16, packed low|high into one u32
__device__ __forceinline__ unsigned rne2(float a, float b) {
  unsigned ua = __float_as_uint(a), ub = __float_as_uint(b);
  ua = ua + 0x7FFFu + ((ua >> 16) & 1u);
  ub = ub + 0x7FFFu + ((ub >> 16) & 1u);
  return (ua >> 16) | (ub & 0xFFFF0000u);
}

// single-instruction RNE pack (gfx950; no builtin — T12/m240). low16=a, high16=b
__device__ __forceinline__ unsigned cvt_pk_bf16(float a, float b) {
  unsigned r;
  asm("v_cvt_pk_bf16_f32 %0, %1, %2" : "=v"(r) : "v"(a), "v"(b));
  return r;
}

// ------------- fused prep: cvt(x,K) | transpose(Wq,Wo,V) | masks -------------
__global__ __launch_bounds__(256) void prep_k(const float* __restrict__ x, bf16* __restrict__ xb,
                                              const float* __restrict__ Kf, bf16* __restrict__ Kb,
                                              const float* __restrict__ Wq, bf16* __restrict__ WqT,
                                              const float* __restrict__ Wo, bf16* __restrict__ WoT,
                                              const float* __restrict__ V, bf16* __restrict__ VTb,
                                              const int* __restrict__ kvm, const int* __restrict__ qm,
                                              float* __restrict__ kvB, float* __restrict__ qB) {
  __shared__ float tile[64][65];
  int bid = blockIdx.x, tid = threadIdx.x;
  if (bid < 8192) {  // fp32 -> bf16 elementwise, 4 elems/thread
    const float* s; bf16* d; int g = bid;
    if (g < 4096) { s = x; d = xb; } else { s = Kf; d = Kb; g -= 4096; }
    int i = (g * 256 + tid) * 4;
    float4 v = *(const float4*)(s + i);
    uint2 o = {rne2(v.x, v.y), rne2(v.z, v.w)};
    *(uint2*)(d + i) = o;
    return;
  }
  if (bid < 9744 - 16) {  // 64x64 convert+transpose tiles
    const float* s; bf16* d; int r0, c0, R, C;
    if (bid < 8704) {
      int idx = bid - 8192;
      s = (idx >> 8) ? Wo : Wq; d = (idx >> 8) ? WoT : WqT;
      int rem = idx & 255;
      r0 = (rem & 15) * 64; c0 = (rem >> 4) * 64; R = 1024; C = 1024;
    } else {
      int idx = bid - 8704;
      int m = idx >> 5;
      s = V + (size_t)m * 2048 * 64; d = VTb + (size_t)m * 2048 * 64;
      r0 = (idx & 31) * 64; c0 = 0; R = 2048; C = 64;
    }
    int tr = tid >> 2, tg = tid & 3;
#pragma unroll
    for (int k = 0; k < 4; ++k) {
      int col = tg * 16 + k * 4;
      float4 v = *(const float4*)(s + (size_t)(r0 + tr) * C + c0 + col);
      tile[tr][col] = v.x; tile[tr][col + 1] = v.y;
      tile[tr][col + 2] = v.z; tile[tr][col + 3] = v.w;
    }
    __syncthreads();
    int orow = tid >> 2, ch = tid & 3;
    bf16* drow = d + (size_t)(c0 + orow) * R + r0;
    uint4 w0, w1;
    w0.x = rne2(tile[ch * 8 + 0][orow], tile[ch * 8 + 1][orow]);
    w0.y = rne2(tile[ch * 8 + 2][orow], tile[ch * 8 + 3][orow]);
    w0.z = rne2(tile[ch * 8 + 4][orow], tile[ch * 8 + 5][orow]);
    w0.w = rne2(tile[ch * 8 + 6][orow], tile[ch * 8 + 7][orow]);
    w1.x = rne2(tile[32 + ch * 8 + 0][orow], tile[32 + ch * 8 + 1][orow]);
    w1.y = rne2(tile[32 + ch * 8 + 2][orow], tile[32 + ch * 8 + 3][orow]);
    w1.z = rne2(tile[32 + ch * 8 + 4][orow], tile[32 + ch * 8 + 5][orow]);
    w1.w = rne2(tile[32 + ch * 8 + 6][orow], tile[32 + ch * 8 + 7][orow]);
    *(uint4*)(drow + ch * 8) = w0;
    *(uint4*)(drow + 32 + ch * 8) = w1;
    return;
  }
  int i = (bid - (9744 - 16)) * 256 + tid;  // mask -> additive log2 bias
  kvB[i] = kvm[i] ? 0.0f : -3000.0f;
  qB[i]  = qm[i]  ? 0.0f : -3000.0f;
}

// --- GEMM: C[M,N] = scale*(A @ BT^T), 128x64 tile, BK=64, LDS dbuf ---------
// R11 verdict: GEMMs are small (~10-20 µs) and structure-insensitive at this
// shape (64²/128²/128x64 all within ±4 µs of total). Keeping 128x64 (best
// measured point). 12 ds_read : 16 MFMA per wave-iter, 2 blk/CU, vmcnt(6).
__device__ __forceinline__ void storeC(bf16* C, size_t i, float v) { C[i] = __float2bfloat16(v); }
__device__ __forceinline__ void storeC(float* C, size_t i, float v) { C[i] = v; }

template <typename OT>
__global__ __launch_bounds__(256, 2) void gemm_bt_k(const bf16* __restrict__ A,
                                                    const bf16* __restrict__ BT,
                                                    OT* __restrict__ C,
                                                    int M, int N, int K, float scale) {
  __shared__ __align__(16) bf16 As[2][128 * 64];
  __shared__ __align__(16) bf16 Bs[2][64 * 64];
  int tid = threadIdx.x;
  int wave = tid >> 6, lane = tid & 63;
  int quad = lane >> 4, lm = lane & 15;
  int wm = wave >> 1, wn = wave & 1;

  // bijective XCD swizzle: each XCD gets 64 consecutive logical tiles
  int bid = blockIdx.y * gridDim.x + blockIdx.x;
  int cpx = (gridDim.x * gridDim.y) >> 3;
  int swz = (bid & 7) * cpx + (bid >> 3);
  int bx = swz % gridDim.x, by = swz / gridDim.x;
  int row0 = by * 128, col0 = bx * 64;

  floatx4 acc[4][2];
#pragma unroll
  for (int mt = 0; mt < 4; ++mt)
#pragma unroll
    for (int nt = 0; nt < 2; ++nt) acc[mt][nt] = (floatx4){0.f, 0.f, 0.f, 0.f};

  auto stageAB = [&](int buf, int k0) {
#pragma unroll
    for (int ch = 0; ch < 4; ++ch) {  // A: 1024 chunks, 4/thread
      int c = ch * 256 + tid;
      int r = c >> 3, g16 = c & 7;
      int sc = (g16 ^ (r & 7)) * 8;
      async_lds16(A + (size_t)(row0 + r) * K + k0 + sc,
                  &As[buf][(ch * 256 + wave * 64) * 8]);
    }
#pragma unroll
    for (int ch = 0; ch < 2; ++ch) {  // B: 512 chunks, 2/thread
      int c = ch * 256 + tid;
      int r = c >> 3, g16 = c & 7;
      int sc = (g16 ^ (r & 7)) * 8;
      async_lds16(BT + (size_t)(col0 + r) * K + k0 + sc,
                  &Bs[buf][(ch * 256 + wave * 64) * 8]);
    }
  };

  int niter = K >> 6;
  stageAB(0, 0);
  for (int i = 0; i < niter; ++i) {
    __builtin_amdgcn_s_barrier();  // all waves done reading buf (i+1)&1
    if (i + 1 < niter) {
      stageAB((i + 1) & 1, (i + 1) << 6);
      __builtin_amdgcn_s_waitcnt(WAIT_VM6);  // cur buffer's loads (prev iter) done
    } else {
      __builtin_amdgcn_s_waitcnt(WAIT_VM0);
    }
    __builtin_amdgcn_s_barrier();  // every wave's cur staging landed
    const bf16* Ac = As[i & 1];
    const bf16* Bc = Bs[i & 1];
    int sw = lm & 7;
#pragma unroll
    for (int ks = 0; ks < 64; ks += 32) {
      short8 af[4], bfr[2];
#pragma unroll
      for (int mt = 0; mt < 4; ++mt) {
        int R = wm * 64 + mt * 16 + lm;
        af[mt] = *(const short8*)&Ac[R * 64 + ((((ks >> 3) + quad) ^ sw) * 8)];
      }
#pragma unroll
      for (int nt = 0; nt < 2; ++nt) {
        int R = wn * 32 + nt * 16 + lm;
        bfr[nt] = *(const short8*)&Bc[R * 64 + ((((ks >> 3) + quad) ^ sw) * 8)];
      }
#pragma unroll
      for (int mt = 0; mt < 4; ++mt)
#pragma unroll
        for (int nt = 0; nt < 2; ++nt)
          acc[mt][nt] = MFMA16(af[mt], bfr[nt], acc[mt][nt]);
    }
  }
#pragma unroll
  for (int mt = 0; mt < 4; ++mt)
#pragma unroll
    for (int nt = 0; nt < 2; ++nt)
#pragma unroll
      for (int j = 0; j < 4; ++j) {
        int rr = row0 + wm * 64 + mt * 16 + quad * 4 + j;
        int cc = col0 + wn * 32 + nt * 16 + lm;
        storeC(C, (size_t)rr * N + cc, acc[mt][nt][j] * scale);
      }
}

// ------- flash attention: 3-buf LDS pipeline, ONE barrier per kv-iter -------
// R11 diagnosis: 2-barrier dbuf left no pipe above 43% busy at 8 waves/CU —
// barrier-skew latency-bound. R12: distance-2 prefetch, 3 buffers, 1 barrier.
// Invariants (derived + tail/prologue checked):
//  iter i: barrier publishes (a) all compute(i-1) done -> WAR-safe to stage
//  into buf[(i+2)%3]=buf[(i-1)%3]; (b) all waves' iter-(i-1) vmcnt(4)
//  certification of stage(i) -> tile i readable. In-loop vmcnt(4) after
//  stage(i+2) certifies stage(i+1) (vmem counter drains in issue order,
//  m135). Prologue: stage(0),stage(1),vmcnt(4),syncthreads closes tile-0;
//  tail: vmcnt(0) once staging stops certifies stage(31) an iter early.
// LDS 56 KB -> 2 blk/CU (112 KB). Loads never drain to 0 in-loop.
__global__ __launch_bounds__(256, 2) void attn_k(const bf16* __restrict__ Q,
                                                 const bf16* __restrict__ Km,
                                                 const bf16* __restrict__ VT,
                                                 const float* __restrict__ qB,
                                                 const float* __restrict__ kvB,
                                                 bf16* __restrict__ O) {
  const float TINY = 9.313225746154785e-10f;  // 2^-30
  __shared__ __align__(16) bf16 Ks[3][64 * 64];
  __shared__ __align__(16) bf16 Vs[3][64 * 64];
  __shared__ __align__(16) float kvBs[2048];

  int tid = threadIdx.x;
  int wave = tid >> 6, lane = tid & 63;
  int quad = lane >> 4, lm = lane & 15;
  int qb = blockIdx.x, h = blockIdx.y, b = blockIdx.z;
  int q0 = qb * 128 + wave * 32;

  const bf16* kbase = Km + (size_t)(b * 16 + h) * 2048 * 64;
  const bf16* vbase = VT + (size_t)(b * 16 + h) * 64 * 2048;
  const float* kvBb = kvB + b * 2048;

  // stage all 2048 kv biases to LDS with plain loads + ds_write
  {
    float4 v0 = *(const float4*)(kvBb + tid * 8);
    float4 v1 = *(const float4*)(kvBb + tid * 8 + 4);
    *(float4*)&kvBs[tid * 8] = v0;
    *(float4*)&kvBs[tid * 8 + 4] = v1;
  }

  short8 aq0[2], aq1[2];  // [qh]: Q B-frags for q-cols qh*16+lm, k 0-31 / 32-63
  float qfac[2];
#pragma unroll
  for (int qh = 0; qh < 2; ++qh) {
    const bf16* qp = Q + (size_t)(b * 2048 + q0 + qh * 16 + lm) * 1024 + h * 64 + quad * 8;
    aq0[qh] = *(const short8*)qp;
    aq1[qh] = *(const short8*)(qp + 32);
    qfac[qh] = (qB[b * 2048 + q0 + qh * 16 + lm] == 0.0f) ? 1.0f : 0.0f;
  }

  short8 ones;
#pragma unroll
  for (int i = 0; i < 8; ++i) ones[i] = (short)0x3F80;  // bf16 1.0

  floatx4 o_acc[2][4];
  floatx4 l_acc[2];
#pragma unroll
  for (int qh = 0; qh < 2; ++qh) {
    l_acc[qh] = (floatx4){0.f, 0.f, 0.f, 0.f};
#pragma unroll
    for (int t = 0; t < 4; ++t) o_acc[qh][t] = (floatx4){0.f, 0.f, 0.f, 0.f};
  }

  union S8U { short8 s8; s16x4 h[2]; unsigned u[4]; };

  auto stageKV = [&](int buf, int kv0) {
#pragma unroll
    for (int c = 0; c < 2; ++c) {  // 4 loads/wave total (2 K + 2 V)
      int o = (wave * 2 + c) * 1024 + lane * 16;  // byte offset in 8KB tile
      int r = o >> 7;                              // tile row 0..63
      int g16 = (o >> 4) & 7;                      // 16B chunk in row
      int sc = ((g16 ^ (r & 7)) * 8);              // swizzled source elem col
      async_lds16(kbase + (size_t)(kv0 + r) * 64 + sc, &Ks[buf][(wave * 2 + c) * 512]);
      async_lds16(vbase + (size_t)r * 2048 + kv0 + sc, &Vs[buf][(wave * 2 + c) * 512]);
    }
  };

  __syncthreads();          // kvBs visible; Q/bias loads still counted below
  stageKV(0, 0);
  stageKV(1, 64);
  __builtin_amdgcn_s_waitcnt(WAIT_VM4);  // own stage(0) done (8 outstanding -> 4)
  __syncthreads();                        // publish tile 0 across waves
  int buf = 0;
  for (int i = 0; i < 32; ++i) {
    int kv0 = i * 64;
    __builtin_amdgcn_s_barrier();  // publish stage(i); all compute(i-1) done
    if (i + 2 < 32) {
      stageKV(buf == 0 ? 2 : buf - 1, kv0 + 128);  // (i+2)%3
      __builtin_amdgcn_s_waitcnt(WAIT_VM4);        // certify stage(i+1)
    } else {
      __builtin_amdgcn_s_waitcnt(WAIT_VM0);        // certify final tiles
    }
    const bf16* Kc = Ks[buf];
    const bf16* Vc = Vs[buf];

    // ---- S^T = K.Q^T per kv-tile t, both q-halves share the K frags ----
    S8U pf[2][2];  // [qh][kvhalf]
#pragma unroll
    for (int t = 0; t < 4; ++t) {
      int R = t * 16 + lm, sw = lm & 7;
      short8 kf0 = *(const short8*)&Kc[R * 64 + ((quad ^ sw) * 8)];
      short8 kf1 = *(const short8*)&Kc[R * 64 + (((quad + 4) ^ sw) * 8)];
      floatx4 zb = *(const floatx4*)&kvBs[kv0 + t * 16 + quad * 4];
      __builtin_amdgcn_s_setprio(1);
      floatx4 z0 = MFMA16(kf0, aq0[0], zb);
      z0 = MFMA16(kf1, aq1[0], z0);
      floatx4 z1 = MFMA16(kf0, aq0[1], zb);
      z1 = MFMA16(kf1, aq1[1], z1);
      __builtin_amdgcn_s_setprio(0);
      float p00 = fmaf(qfac[0], __builtin_amdgcn_exp2f(z0[0]), TINY);
      float p01 = fmaf(qfac[0], __builtin_amdgcn_exp2f(z0[1]), TINY);
      float p02 = fmaf(qfac[0], __builtin_amdgcn_exp2f(z0[2]), TINY);
      float p03 = fmaf(qfac[0], __builtin_amdgcn_exp2f(z0[3]), TINY);
      pf[0][t >> 1].u[(t & 1) * 2 + 0] = cvt_pk_bf16(p00, p01);
      pf[0][t >> 1].u[(t & 1) * 2 + 1] = cvt_pk_bf16(p02, p03);
      float p10 = fmaf(qfac[1], __builtin_amdgcn_exp2f(z1[0]), TINY);
      float p11 = fmaf(qfac[1], __builtin_amdgcn_exp2f(z1[1]), TINY);
      float p12 = fmaf(qfac[1], __builtin_amdgcn_exp2f(z1[2]), TINY);
      float p13 = fmaf(qfac[1], __builtin_amdgcn_exp2f(z1[3]), TINY);
      pf[1][t >> 1].u[(t & 1) * 2 + 0] = cvt_pk_bf16(p10, p11);
      pf[1][t >> 1].u[(t & 1) * 2 + 1] = cvt_pk_bf16(p12, p13);
    }
    // ---- O^T += V^T.P^T ; V frags shared by both q-halves ----
#pragma unroll
    for (int t = 0; t < 4; ++t) {
      int D = t * 16 + lm, sw = lm & 7;
      int hoff = (quad & 1) * 4, qh2 = quad >> 1;
      S8U vf0, vf1;
      vf0.h[0] = *(const s16x4*)&Vc[D * 64 + (((0 + qh2) ^ sw) * 8) + hoff];
      vf0.h[1] = *(const s16x4*)&Vc[D * 64 + (((2 + qh2) ^ sw) * 8) + hoff];
      vf1.h[0] = *(const s16x4*)&Vc[D * 64 + (((4 + qh2) ^ sw) * 8) + hoff];
      vf1.h[1] = *(const s16x4*)&Vc[D * 64 + (((6 + qh2) ^ sw) * 8) + hoff];
      __builtin_amdgcn_s_setprio(1);
      o_acc[0][t] = MFMA16(vf0.s8, pf[0][0].s8, o_acc[0][t]);
      o_acc[0][t] = MFMA16(vf1.s8, pf[0][1].s8, o_acc[0][t]);
      o_acc[1][t] = MFMA16(vf0.s8, pf[1][0].s8, o_acc[1][t]);
      o_acc[1][t] = MFMA16(vf1.s8, pf[1][1].s8, o_acc[1][t]);
      __builtin_amdgcn_s_setprio(0);
    }
    __builtin_amdgcn_s_setprio(1);
    l_acc[0] = MFMA16(ones, pf[0][0].s8, l_acc[0]);
    l_acc[0] = MFMA16(ones, pf[0][1].s8, l_acc[0]);
    l_acc[1] = MFMA16(ones, pf[1][0].s8, l_acc[1]);
    l_acc[1] = MFMA16(ones, pf[1][1].s8, l_acc[1]);
    __builtin_amdgcn_s_setprio(0);
    buf = (buf == 2) ? 0 : buf + 1;
  }
  // ---- epilogue: normalize, write bf16 [b][q][h*64+d] directly ----
#pragma unroll
  for (int qh = 0; qh < 2; ++qh) {
    float rl = 1.0f / l_acc[qh][0];
    bf16* orow = O + (size_t)(b * 2048 + q0 + qh * 16 + lm) * 1024 + h * 64;
#pragma unroll
    for (int t = 0; t < 4; ++t) {
      uint2 ov = {rne2(o_acc[qh][t][0] * rl, o_acc[qh][t][1] * rl),
                  rne2(o_acc[qh][t][2] * rl, o_acc[qh][t][3] * rl)};
      *(uint2*)(orow + t * 16 + quad * 4) = ov;
    }
  }
}

// ---------------- launch ----------------
extern "C" void kernel_launch(void* const* d_in, const int* in_sizes, int n_in,
                              void* d_out, int out_size, void* d_ws, size_t ws_size,
                              hipStream_t stream) {
  const float* x  = (const float*)d_in[0];   // [2,2048,1024] fp32
  const float* K  = (const float*)d_in[1];   // [2,16,2048,64] fp32
  const float* V  = (const float*)d_in[2];   // [2,16,2048,64] fp32
  const float* Wq = (const float*)d_in[3];   // [1024,1024] fp32
  const float* Wo = (const float*)d_in[4];   // [1024,1024] fp32
  const int* kvm  = (const int*)d_in[5];     // [2,1,1,2048] bool -> int32
  const int* qm   = (const int*)d_in[6];     // [2,1,2048,1] bool -> int32

  char* w = (char*)d_ws;
  bf16* xb    = (bf16*)(w);                        // 8 MB; reused as attnb (xb dead after gemm1)
  bf16* attnb = xb;
  bf16* Qb    = (bf16*)(w + (8u << 20));           // 8 MB (pre-scaled by log2e/sqrt(dk))
  bf16* Kb    = (bf16*)(w + (16u << 20));          // 8 MB
  bf16* VTb   = (bf16*)(w + (24u << 20));          // 8 MB [2,16,64,2048]
  bf16* WqT   = (bf16*)(w + (32u << 20));          // 2 MB
  bf16* WoT   = (bf16*)(w + (34u << 20));          // 2 MB
  float* qB   = (float*)(w + (36u << 20));         // 16 KB
  float* kvB  = (float*)(w + (36u << 20) + 16384); // 16 KB

  const float SCL2 = 0.18033688011112042f;  // log2(e)/sqrt(64)

  prep_k<<<9744, 256, 0, stream>>>(x, xb, K, Kb, Wq, WqT, Wo, WoT, V, VTb, kvm, qm, kvB, qB);
  gemm_bt_k<bf16><<<dim3(16, 32), 256, 0, stream>>>(xb, WqT, Qb, 4096, 1024, 1024, SCL2);
  attn_k<<<dim3(16, 16, 2), 256, 0, stream>>>(Qb, Kb, VTb, qB, kvB, attnb);
  gemm_bt_k<float><<<dim3(16, 32), 256, 0, stream>>>(attnb, WoT, (float*)d_out, 4096, 1024, 1024, 1.0f);
}

// Round 14
// 186.053 us; speedup vs baseline: 1.0082x; 1.0082x over previous
//
#include <hip/hip_runtime.h>
#include <hip/hip_bf16.h>
#include <stdint.h>

typedef __hip_bfloat16 bf16;
typedef __attribute__((ext_vector_type(8))) short short8;
typedef __attribute__((ext_vector_type(4))) short s16x4;
typedef __attribute__((ext_vector_type(4))) float floatx4;

#define MFMA16(a, b, c) __builtin_amdgcn_mfma_f32_16x16x32_bf16(a, b, c, 0, 0, 0)
// s_waitcnt imm: vmcnt[3:0], expcnt[6:4]=7 (no wait), lgkmcnt[11:8]=15 (no wait)
#define WAIT_VM6 3958  // 6 | (7<<4) | (15<<8)
#define WAIT_VM4 3956  // 4 | (7<<4) | (15<<8)
#define WAIT_VM0 3952  // 0 | (7<<4) | (15<<8)

__device__ __forceinline__ void async_lds16(const void* g, void* l) {
  __builtin_amdgcn_global_load_lds((__attribute__((address_space(1))) const void*)g,
                                   (__attribute__((address_space(3))) void*)l, 16, 0, 0);
}

// RNE-round two non-NaN floats to bf16, packed low|high into one u32
__device__ __forceinline__ unsigned rne2(float a, float b) {
  unsigned ua = __float_as_uint(a), ub = __float_as_uint(b);
  ua = ua + 0x7FFFu + ((ua >> 16) & 1u);
  ub = ub + 0x7FFFu + ((ub >> 16) & 1u);
  return (ua >> 16) | (ub & 0xFFFF0000u);
}

// single-instruction RNE pack (gfx950; no builtin — T12/m240). low16=a, high16=b
__device__ __forceinline__ unsigned cvt_pk_bf16(float a, float b) {
  unsigned r;
  asm("v_cvt_pk_bf16_f32 %0, %1, %2" : "=v"(r) : "v"(a), "v"(b));
  return r;
}

// ------------- fused prep: cvt(x,K) | transpose(Wq,Wo,V) | masks -------------
__global__ __launch_bounds__(256) void prep_k(const float* __restrict__ x, bf16* __restrict__ xb,
                                              const float* __restrict__ Kf, bf16* __restrict__ Kb,
                                              const float* __restrict__ Wq, bf16* __restrict__ WqT,
                                              const float* __restrict__ Wo, bf16* __restrict__ WoT,
                                              const float* __restrict__ V, bf16* __restrict__ VTb,
                                              const int* __restrict__ kvm, const int* __restrict__ qm,
                                              float* __restrict__ kvB, float* __restrict__ qB) {
  __shared__ float tile[64][65];
  int bid = blockIdx.x, tid = threadIdx.x;
  if (bid < 8192) {  // fp32 -> bf16 elementwise, 4 elems/thread
    const float* s; bf16* d; int g = bid;
    if (g < 4096) { s = x; d = xb; } else { s = Kf; d = Kb; g -= 4096; }
    int i = (g * 256 + tid) * 4;
    float4 v = *(const float4*)(s + i);
    uint2 o = {rne2(v.x, v.y), rne2(v.z, v.w)};
    *(uint2*)(d + i) = o;
    return;
  }
  if (bid < 9744 - 16) {  // 64x64 convert+transpose tiles
    const float* s; bf16* d; int r0, c0, R, C;
    if (bid < 8704) {
      int idx = bid - 8192;
      s = (idx >> 8) ? Wo : Wq; d = (idx >> 8) ? WoT : WqT;
      int rem = idx & 255;
      r0 = (rem & 15) * 64; c0 = (rem >> 4) * 64; R = 1024; C = 1024;
    } else {
      int idx = bid - 8704;
      int m = idx >> 5;
      s = V + (size_t)m * 2048 * 64; d = VTb + (size_t)m * 2048 * 64;
      r0 = (idx & 31) * 64; c0 = 0; R = 2048; C = 64;
    }
    int tr = tid >> 2, tg = tid & 3;
#pragma unroll
    for (int k = 0; k < 4; ++k) {
      int col = tg * 16 + k * 4;
      float4 v = *(const float4*)(s + (size_t)(r0 + tr) * C + c0 + col);
      tile[tr][col] = v.x; tile[tr][col + 1] = v.y;
      tile[tr][col + 2] = v.z; tile[tr][col + 3] = v.w;
    }
    __syncthreads();
    int orow = tid >> 2, ch = tid & 3;
    bf16* drow = d + (size_t)(c0 + orow) * R + r0;
    uint4 w0, w1;
    w0.x = rne2(tile[ch * 8 + 0][orow], tile[ch * 8 + 1][orow]);
    w0.y = rne2(tile[ch * 8 + 2][orow], tile[ch * 8 + 3][orow]);
    w0.z = rne2(tile[ch * 8 + 4][orow], tile[ch * 8 + 5][orow]);
    w0.w = rne2(tile[ch * 8 + 6][orow], tile[ch * 8 + 7][orow]);
    w1.x = rne2(tile[32 + ch * 8 + 0][orow], tile[32 + ch * 8 + 1][orow]);
    w1.y = rne2(tile[32 + ch * 8 + 2][orow], tile[32 + ch * 8 + 3][orow]);
    w1.z = rne2(tile[32 + ch * 8 + 4][orow], tile[32 + ch * 8 + 5][orow]);
    w1.w = rne2(tile[32 + ch * 8 + 6][orow], tile[32 + ch * 8 + 7][orow]);
    *(uint4*)(drow + ch * 8) = w0;
    *(uint4*)(drow + 32 + ch * 8) = w1;
    return;
  }
  int i = (bid - (9744 - 16)) * 256 + tid;  // mask -> additive log2 bias
  kvB[i] = kvm[i] ? 0.0f : -3000.0f;
  qB[i]  = qm[i]  ? 0.0f : -3000.0f;
}

// --- GEMM: C[M,N] = scale*(A @ BT^T), 128x64 tile, BK=64, LDS dbuf ---------
// R11 verdict: GEMMs are small (~10-20 µs) and structure-insensitive at this
// shape. Keeping 128x64 (best measured point). 12 ds_read : 16 MFMA per
// wave-iter, 2 blk/CU, counted vmcnt(6).
__device__ __forceinline__ void storeC(bf16* C, size_t i, float v) { C[i] = __float2bfloat16(v); }
__device__ __forceinline__ void storeC(float* C, size_t i, float v) { C[i] = v; }

template <typename OT>
__global__ __launch_bounds__(256, 2) void gemm_bt_k(const bf16* __restrict__ A,
                                                    const bf16* __restrict__ BT,
                                                    OT* __restrict__ C,
                                                    int M, int N, int K, float scale) {
  __shared__ __align__(16) bf16 As[2][128 * 64];
  __shared__ __align__(16) bf16 Bs[2][64 * 64];
  int tid = threadIdx.x;
  int wave = tid >> 6, lane = tid & 63;
  int quad = lane >> 4, lm = lane & 15;
  int wm = wave >> 1, wn = wave & 1;

  // bijective XCD swizzle: each XCD gets 64 consecutive logical tiles
  int bid = blockIdx.y * gridDim.x + blockIdx.x;
  int cpx = (gridDim.x * gridDim.y) >> 3;
  int swz = (bid & 7) * cpx + (bid >> 3);
  int bx = swz % gridDim.x, by = swz / gridDim.x;
  int row0 = by * 128, col0 = bx * 64;

  floatx4 acc[4][2];
#pragma unroll
  for (int mt = 0; mt < 4; ++mt)
#pragma unroll
    for (int nt = 0; nt < 2; ++nt) acc[mt][nt] = (floatx4){0.f, 0.f, 0.f, 0.f};

  auto stageAB = [&](int buf, int k0) {
#pragma unroll
    for (int ch = 0; ch < 4; ++ch) {  // A: 1024 chunks, 4/thread
      int c = ch * 256 + tid;
      int r = c >> 3, g16 = c & 7;
      int sc = (g16 ^ (r & 7)) * 8;
      async_lds16(A + (size_t)(row0 + r) * K + k0 + sc,
                  &As[buf][(ch * 256 + wave * 64) * 8]);
    }
#pragma unroll
    for (int ch = 0; ch < 2; ++ch) {  // B: 512 chunks, 2/thread
      int c = ch * 256 + tid;
      int r = c >> 3, g16 = c & 7;
      int sc = (g16 ^ (r & 7)) * 8;
      async_lds16(BT + (size_t)(col0 + r) * K + k0 + sc,
                  &Bs[buf][(ch * 256 + wave * 64) * 8]);
    }
  };

  int niter = K >> 6;
  stageAB(0, 0);
  for (int i = 0; i < niter; ++i) {
    __builtin_amdgcn_s_barrier();  // all waves done reading buf (i+1)&1
    if (i + 1 < niter) {
      stageAB((i + 1) & 1, (i + 1) << 6);
      __builtin_amdgcn_s_waitcnt(WAIT_VM6);  // cur buffer's loads (prev iter) done
    } else {
      __builtin_amdgcn_s_waitcnt(WAIT_VM0);
    }
    __builtin_amdgcn_s_barrier();  // every wave's cur staging landed
    const bf16* Ac = As[i & 1];
    const bf16* Bc = Bs[i & 1];
    int sw = lm & 7;
#pragma unroll
    for (int ks = 0; ks < 64; ks += 32) {
      short8 af[4], bfr[2];
#pragma unroll
      for (int mt = 0; mt < 4; ++mt) {
        int R = wm * 64 + mt * 16 + lm;
        af[mt] = *(const short8*)&Ac[R * 64 + ((((ks >> 3) + quad) ^ sw) * 8)];
      }
#pragma unroll
      for (int nt = 0; nt < 2; ++nt) {
        int R = wn * 32 + nt * 16 + lm;
        bfr[nt] = *(const short8*)&Bc[R * 64 + ((((ks >> 3) + quad) ^ sw) * 8)];
      }
#pragma unroll
      for (int mt = 0; mt < 4; ++mt)
#pragma unroll
        for (int nt = 0; nt < 2; ++nt)
          acc[mt][nt] = MFMA16(af[mt], bfr[nt], acc[mt][nt]);
    }
  }
#pragma unroll
  for (int mt = 0; mt < 4; ++mt)
#pragma unroll
    for (int nt = 0; nt < 2; ++nt)
#pragma unroll
      for (int j = 0; j < 4; ++j) {
        int rr = row0 + wm * 64 + mt * 16 + quad * 4 + j;
        int cc = col0 + wn * 32 + nt * 16 + lm;
        storeC(C, (size_t)rr * N + cc, acc[mt][nt][j] * scale);
      }
}

// ------- flash attention: kv-SPLIT, 8 waves/block, dbuf 2-barrier -----------
// R12 verdict: 1-barrier 3-buf was null -> stall is wave starvation (2
// waves/SIMD vs the serial ds_read->MFMA->exp2->pack->MFMA chain).
// R13: split kv across wave pairs. 512 thr: wave w: q-group qg=w&3 (32
// q-rows), kv-half s=w>>2 (sums kv [s*1024, s*1024+1024) over 16 iters).
// l and O are PLAIN SUMS (bias-based softmax, no running max) -> halves
// combine by addition via one LDS exchange in the epilogue (K/V LDS dead).
// 2 staging streams, each staged by its 4 waves -> per-wave vmcnt(4)
// discipline unchanged; block barrier serves both streams in lockstep.
// LDS 72 KB -> 2 blk/CU = 16 waves/CU (4/SIMD, was 2). Per-CU LDS traffic
// unchanged (16w x 16it == 8w x 32it). LB(512,4) -> 2 blocks co-resident.
__global__ __launch_bounds__(512, 4) void attn_k(const bf16* __restrict__ Q,
                                                 const bf16* __restrict__ Km,
                                                 const bf16* __restrict__ VT,
                                                 const float* __restrict__ qB,
                                                 const float* __restrict__ kvB,
                                                 bf16* __restrict__ O) {
  const float TINY = 9.313225746154785e-10f;  // 2^-30
  __shared__ __align__(16) bf16 Ks[2][2][64 * 64];  // [stream][buf]
  __shared__ __align__(16) bf16 Vs[2][2][64 * 64];
  __shared__ __align__(16) float kvBs[2048];

  int tid = threadIdx.x;
  int wave = tid >> 6, lane = tid & 63;
  int quad = lane >> 4, lm = lane & 15;
  int strm = wave >> 2, sub = wave & 3;
  int qb = blockIdx.x, h = blockIdx.y, b = blockIdx.z;
  int q0 = qb * 128 + sub * 32;

  const bf16* kbase = Km + (size_t)(b * 16 + h) * 2048 * 64;
  const bf16* vbase = VT + (size_t)(b * 16 + h) * 64 * 2048;
  const float* kvBb = kvB + b * 2048;

  // stage all 2048 kv biases to LDS (512 threads x 4 floats)
  {
    float4 v0 = *(const float4*)(kvBb + tid * 4);
    *(float4*)&kvBs[tid * 4] = v0;
  }

  short8 aq0[2], aq1[2];  // [qh]: Q B-frags for q-rows q0+qh*16+lm
  float qfac[2];
#pragma unroll
  for (int qh = 0; qh < 2; ++qh) {
    const bf16* qp = Q + (size_t)(b * 2048 + q0 + qh * 16 + lm) * 1024 + h * 64 + quad * 8;
    aq0[qh] = *(const short8*)qp;
    aq1[qh] = *(const short8*)(qp + 32);
    qfac[qh] = (qB[b * 2048 + q0 + qh * 16 + lm] == 0.0f) ? 1.0f : 0.0f;
  }

  floatx4 o_acc[2][4];
  floatx4 l_acc[2];
#pragma unroll
  for (int qh = 0; qh < 2; ++qh) {
    l_acc[qh] = (floatx4){0.f, 0.f, 0.f, 0.f};
#pragma unroll
    for (int t = 0; t < 4; ++t) o_acc[qh][t] = (floatx4){0.f, 0.f, 0.f, 0.f};
  }

  short8 ones;
#pragma unroll
  for (int i = 0; i < 8; ++i) ones[i] = (short)0x3F80;  // bf16 1.0

  union S8U { short8 s8; s16x4 h[2]; unsigned u[4]; };

  // wave stages its quarter of its stream's 64-kv tile (4 loads -> vmcnt(4))
  auto stageKV = [&](int buf, int it) {
    int kv0 = strm * 1024 + it * 64;
#pragma unroll
    for (int c = 0; c < 2; ++c) {
      int o = (sub * 2 + c) * 1024 + lane * 16;  // byte offset in 8KB tile
      int r = o >> 7;                             // tile row 0..63
      int g16 = (o >> 4) & 7;                     // 16B chunk in row
      int sc = ((g16 ^ (r & 7)) * 8);             // swizzled source elem col
      async_lds16(kbase + (size_t)(kv0 + r) * 64 + sc, &Ks[strm][buf][(sub * 2 + c) * 512]);
      async_lds16(vbase + (size_t)r * 2048 + kv0 + sc, &Vs[strm][buf][(sub * 2 + c) * 512]);
    }
  };

  __syncthreads();  // kvBs visible; drains Q/bias loads (vmcnt=0)
  stageKV(0, 0);
  for (int i = 0; i < 16; ++i) {
    int kv0 = strm * 1024 + i * 64;
    __builtin_amdgcn_s_barrier();  // all waves done reading buf (i+1)&1
    if (i + 1 < 16) {
      stageKV((i + 1) & 1, i + 1);
      __builtin_amdgcn_s_waitcnt(WAIT_VM4);  // cur buffer's loads (prev iter) done
    } else {
      __builtin_amdgcn_s_waitcnt(WAIT_VM0);
    }
    __builtin_amdgcn_s_barrier();  // every wave's cur staging landed
    const bf16* Kc = Ks[strm][i & 1];
    const bf16* Vc = Vs[strm][i & 1];

    // ---- S^T = K.Q^T per kv-tile t, both q-halves share the K frags ----
    S8U pf[2][2];  // [qh][kvhalf]
#pragma unroll
    for (int t = 0; t < 4; ++t) {
      int R = t * 16 + lm, sw = lm & 7;
      short8 kf0 = *(const short8*)&Kc[R * 64 + ((quad ^ sw) * 8)];
      short8 kf1 = *(const short8*)&Kc[R * 64 + (((quad + 4) ^ sw) * 8)];
      floatx4 zb = *(const floatx4*)&kvBs[kv0 + t * 16 + quad * 4];
      __builtin_amdgcn_s_setprio(1);
      floatx4 z0 = MFMA16(kf0, aq0[0], zb);
      z0 = MFMA16(kf1, aq1[0], z0);
      floatx4 z1 = MFMA16(kf0, aq0[1], zb);
      z1 = MFMA16(kf1, aq1[1], z1);
      __builtin_amdgcn_s_setprio(0);
      float p00 = fmaf(qfac[0], __builtin_amdgcn_exp2f(z0[0]), TINY);
      float p01 = fmaf(qfac[0], __builtin_amdgcn_exp2f(z0[1]), TINY);
      float p02 = fmaf(qfac[0], __builtin_amdgcn_exp2f(z0[2]), TINY);
      float p03 = fmaf(qfac[0], __builtin_amdgcn_exp2f(z0[3]), TINY);
      pf[0][t >> 1].u[(t & 1) * 2 + 0] = cvt_pk_bf16(p00, p01);
      pf[0][t >> 1].u[(t & 1) * 2 + 1] = cvt_pk_bf16(p02, p03);
      float p10 = fmaf(qfac[1], __builtin_amdgcn_exp2f(z1[0]), TINY);
      float p11 = fmaf(qfac[1], __builtin_amdgcn_exp2f(z1[1]), TINY);
      float p12 = fmaf(qfac[1], __builtin_amdgcn_exp2f(z1[2]), TINY);
      float p13 = fmaf(qfac[1], __builtin_amdgcn_exp2f(z1[3]), TINY);
      pf[1][t >> 1].u[(t & 1) * 2 + 0] = cvt_pk_bf16(p10, p11);
      pf[1][t >> 1].u[(t & 1) * 2 + 1] = cvt_pk_bf16(p12, p13);
    }
    // ---- O^T += V^T.P^T ; V frags shared by both q-halves ----
#pragma unroll
    for (int t = 0; t < 4; ++t) {
      int D = t * 16 + lm, sw = lm & 7;
      int hoff = (quad & 1) * 4, qh2 = quad >> 1;
      S8U vf0, vf1;
      vf0.h[0] = *(const s16x4*)&Vc[D * 64 + (((0 + qh2) ^ sw) * 8) + hoff];
      vf0.h[1] = *(const s16x4*)&Vc[D * 64 + (((2 + qh2) ^ sw) * 8) + hoff];
      vf1.h[0] = *(const s16x4*)&Vc[D * 64 + (((4 + qh2) ^ sw) * 8) + hoff];
      vf1.h[1] = *(const s16x4*)&Vc[D * 64 + (((6 + qh2) ^ sw) * 8) + hoff];
      __builtin_amdgcn_s_setprio(1);
      o_acc[0][t] = MFMA16(vf0.s8, pf[0][0].s8, o_acc[0][t]);
      o_acc[0][t] = MFMA16(vf1.s8, pf[0][1].s8, o_acc[0][t]);
      o_acc[1][t] = MFMA16(vf0.s8, pf[1][0].s8, o_acc[1][t]);
      o_acc[1][t] = MFMA16(vf1.s8, pf[1][1].s8, o_acc[1][t]);
      __builtin_amdgcn_s_setprio(0);
    }
    __builtin_amdgcn_s_setprio(1);
    l_acc[0] = MFMA16(ones, pf[0][0].s8, l_acc[0]);
    l_acc[0] = MFMA16(ones, pf[0][1].s8, l_acc[0]);
    l_acc[1] = MFMA16(ones, pf[1][0].s8, l_acc[1]);
    l_acc[1] = MFMA16(ones, pf[1][1].s8, l_acc[1]);
    __builtin_amdgcn_s_setprio(0);
  }

  // ---- epilogue: combine kv-halves via LDS (K/V buffers dead), write O ----
  __syncthreads();  // all waves done with K/V LDS + staging landed
  float* shO = (float*)&Ks[0][0][0];  // 32 KB: 256 rows x 32 floats
  float* shL = (float*)&Vs[0][0][0];  // 2 KB used
  int base = sub * 64 + lane;
  if (strm == 1) {
#pragma unroll
    for (int qh = 0; qh < 2; ++qh) {
#pragma unroll
      for (int t = 0; t < 4; ++t)
        *(floatx4*)&shO[(base * 8 + qh * 4 + t) * 4] = o_acc[qh][t];
      shL[base * 2 + qh] = l_acc[qh][0];
    }
  }
  __syncthreads();
  if (strm == 0) {
#pragma unroll
    for (int qh = 0; qh < 2; ++qh) {
      float l = l_acc[qh][0] + shL[base * 2 + qh];
      float rl = 1.0f / l;
      bf16* orow = O + (size_t)(b * 2048 + q0 + qh * 16 + lm) * 1024 + h * 64;
#pragma unroll
      for (int t = 0; t < 4; ++t) {
        floatx4 p = *(const floatx4*)&shO[(base * 8 + qh * 4 + t) * 4];
        floatx4 o = o_acc[qh][t] + p;
        uint2 ov = {rne2(o[0] * rl, o[1] * rl), rne2(o[2] * rl, o[3] * rl)};
        *(uint2*)(orow + t * 16 + quad * 4) = ov;
      }
    }
  }
}

// ---------------- launch ----------------
extern "C" void kernel_launch(void* const* d_in, const int* in_sizes, int n_in,
                              void* d_out, int out_size, void* d_ws, size_t ws_size,
                              hipStream_t stream) {
  const float* x  = (const float*)d_in[0];   // [2,2048,1024] fp32
  const float* K  = (const float*)d_in[1];   // [2,16,2048,64] fp32
  const float* V  = (const float*)d_in[2];   // [2,16,2048,64] fp32
  const float* Wq = (const float*)d_in[3];   // [1024,1024] fp32
  const float* Wo = (const float*)d_in[4];   // [1024,1024] fp32
  const int* kvm  = (const int*)d_in[5];     // [2,1,1,2048] bool -> int32
  const int* qm   = (const int*)d_in[6];     // [2,1,2048,1] bool -> int32

  char* w = (char*)d_ws;
  bf16* xb    = (bf16*)(w);                        // 8 MB; reused as attnb (xb dead after gemm1)
  bf16* attnb = xb;
  bf16* Qb    = (bf16*)(w + (8u << 20));           // 8 MB (pre-scaled by log2e/sqrt(dk))
  bf16* Kb    = (bf16*)(w + (16u << 20));          // 8 MB
  bf16* VTb   = (bf16*)(w + (24u << 20));          // 8 MB [2,16,64,2048]
  bf16* WqT   = (bf16*)(w + (32u << 20));          // 2 MB
  bf16* WoT   = (bf16*)(w + (34u << 20));          // 2 MB
  float* qB   = (float*)(w + (36u << 20));         // 16 KB
  float* kvB  = (float*)(w + (36u << 20) + 16384); // 16 KB

  const float SCL2 = 0.18033688011112042f;  // log2(e)/sqrt(64)

  prep_k<<<9744, 256, 0, stream>>>(x, xb, K, Kb, Wq, WqT, Wo, WoT, V, VTb, kvm, qm, kvB, qB);
  gemm_bt_k<bf16><<<dim3(16, 32), 256, 0, stream>>>(xb, WqT, Qb, 4096, 1024, 1024, SCL2);
  attn_k<<<dim3(16, 16, 2), 512, 0, stream>>>(Qb, Kb, VTb, qB, kvB, attnb);
  gemm_bt_k<float><<<dim3(16, 32), 256, 0, stream>>>(attnb, WoT, (float*)d_out, 4096, 1024, 1024, 1.0f);
}

// Round 15
// 181.436 us; speedup vs baseline: 1.0339x; 1.0254x over previous
//
#include <hip/hip_runtime.h>
#include <hip/hip_bf16.h>
#include <stdint.h>

typedef __hip_bfloat16 bf16;
typedef __attribute__((ext_vector_type(8))) short short8;
typedef __attribute__((ext_vector_type(4))) short s16x4;
typedef __attribute__((ext_vector_type(4))) float floatx4;

#define MFMA16(a, b, c) __builtin_amdgcn_mfma_f32_16x16x32_bf16(a, b, c, 0, 0, 0)
// s_waitcnt imm: vmcnt[3:0], expcnt[6:4]=7 (no wait), lgkmcnt[11:8]=15 (no wait)
#define WAIT_VM6 3958  // 6 | (7<<4) | (15<<8)
#define WAIT_VM4 3956  // 4 | (7<<4) | (15<<8)
#define WAIT_VM0 3952  // 0 | (7<<4) | (15<<8)

__device__ __forceinline__ void async_lds16(const void* g, void* l) {
  __builtin_amdgcn_global_load_lds((__attribute__((address_space(1))) const void*)g,
                                   (__attribute__((address_space(3))) void*)l, 16, 0, 0);
}

// RNE-round two non-NaN floats to bf16, packed low|high into one u32
__device__ __forceinline__ unsigned rne2(float a, float b) {
  unsigned ua = __float_as_uint(a), ub = __float_as_uint(b);
  ua = ua + 0x7FFFu + ((ua >> 16) & 1u);
  ub = ub + 0x7FFFu + ((ub >> 16) & 1u);
  return (ua >> 16) | (ub & 0xFFFF0000u);
}

// single-instruction RNE pack (gfx950; no builtin — T12/m240). low16=a, high16=b
__device__ __forceinline__ unsigned cvt_pk_bf16(float a, float b) {
  unsigned r;
  asm("v_cvt_pk_bf16_f32 %0, %1, %2" : "=v"(r) : "v"(a), "v"(b));
  return r;
}

// ------------- fused prep: cvt(x,K) | transpose(Wq,Wo,V) | masks -------------
__global__ __launch_bounds__(256) void prep_k(const float* __restrict__ x, bf16* __restrict__ xb,
                                              const float* __restrict__ Kf, bf16* __restrict__ Kb,
                                              const float* __restrict__ Wq, bf16* __restrict__ WqT,
                                              const float* __restrict__ Wo, bf16* __restrict__ WoT,
                                              const float* __restrict__ V, bf16* __restrict__ VTb,
                                              const int* __restrict__ kvm, const int* __restrict__ qm,
                                              float* __restrict__ kvB, float* __restrict__ qB) {
  __shared__ float tile[64][65];
  int bid = blockIdx.x, tid = threadIdx.x;
  if (bid < 8192) {  // fp32 -> bf16 elementwise, 4 elems/thread
    const float* s; bf16* d; int g = bid;
    if (g < 4096) { s = x; d = xb; } else { s = Kf; d = Kb; g -= 4096; }
    int i = (g * 256 + tid) * 4;
    float4 v = *(const float4*)(s + i);
    uint2 o = {rne2(v.x, v.y), rne2(v.z, v.w)};
    *(uint2*)(d + i) = o;
    return;
  }
  if (bid < 9744 - 16) {  // 64x64 convert+transpose tiles
    const float* s; bf16* d; int r0, c0, R, C;
    if (bid < 8704) {
      int idx = bid - 8192;
      s = (idx >> 8) ? Wo : Wq; d = (idx >> 8) ? WoT : WqT;
      int rem = idx & 255;
      r0 = (rem & 15) * 64; c0 = (rem >> 4) * 64; R = 1024; C = 1024;
    } else {
      int idx = bid - 8704;
      int m = idx >> 5;
      s = V + (size_t)m * 2048 * 64; d = VTb + (size_t)m * 2048 * 64;
      r0 = (idx & 31) * 64; c0 = 0; R = 2048; C = 64;
    }
    int tr = tid >> 2, tg = tid & 3;
#pragma unroll
    for (int k = 0; k < 4; ++k) {
      int col = tg * 16 + k * 4;
      float4 v = *(const float4*)(s + (size_t)(r0 + tr) * C + c0 + col);
      tile[tr][col] = v.x; tile[tr][col + 1] = v.y;
      tile[tr][col + 2] = v.z; tile[tr][col + 3] = v.w;
    }
    __syncthreads();
    int orow = tid >> 2, ch = tid & 3;
    bf16* drow = d + (size_t)(c0 + orow) * R + r0;
    uint4 w0, w1;
    w0.x = rne2(tile[ch * 8 + 0][orow], tile[ch * 8 + 1][orow]);
    w0.y = rne2(tile[ch * 8 + 2][orow], tile[ch * 8 + 3][orow]);
    w0.z = rne2(tile[ch * 8 + 4][orow], tile[ch * 8 + 5][orow]);
    w0.w = rne2(tile[ch * 8 + 6][orow], tile[ch * 8 + 7][orow]);
    w1.x = rne2(tile[32 + ch * 8 + 0][orow], tile[32 + ch * 8 + 1][orow]);
    w1.y = rne2(tile[32 + ch * 8 + 2][orow], tile[32 + ch * 8 + 3][orow]);
    w1.z = rne2(tile[32 + ch * 8 + 4][orow], tile[32 + ch * 8 + 5][orow]);
    w1.w = rne2(tile[32 + ch * 8 + 6][orow], tile[32 + ch * 8 + 7][orow]);
    *(uint4*)(drow + ch * 8) = w0;
    *(uint4*)(drow + 32 + ch * 8) = w1;
    return;
  }
  int i = (bid - (9744 - 16)) * 256 + tid;  // mask -> additive log2 bias
  kvB[i] = kvm[i] ? 0.0f : -3000.0f;
  qB[i]  = qm[i]  ? 0.0f : -3000.0f;
}

// --- GEMM: C[M,N] = scale*(A @ BT^T), 128x64 tile, BK=64, LDS dbuf ---------
// R11 verdict: GEMMs are small (~10-20 µs) and structure-insensitive at this
// shape. Keeping 128x64 (best measured point). 12 ds_read : 16 MFMA per
// wave-iter, 2 blk/CU, counted vmcnt(6).
__device__ __forceinline__ void storeC(bf16* C, size_t i, float v) { C[i] = __float2bfloat16(v); }
__device__ __forceinline__ void storeC(float* C, size_t i, float v) { C[i] = v; }

template <typename OT>
__global__ __launch_bounds__(256, 2) void gemm_bt_k(const bf16* __restrict__ A,
                                                    const bf16* __restrict__ BT,
                                                    OT* __restrict__ C,
                                                    int M, int N, int K, float scale) {
  __shared__ __align__(16) bf16 As[2][128 * 64];
  __shared__ __align__(16) bf16 Bs[2][64 * 64];
  int tid = threadIdx.x;
  int wave = tid >> 6, lane = tid & 63;
  int quad = lane >> 4, lm = lane & 15;
  int wm = wave >> 1, wn = wave & 1;

  // bijective XCD swizzle: each XCD gets 64 consecutive logical tiles
  int bid = blockIdx.y * gridDim.x + blockIdx.x;
  int cpx = (gridDim.x * gridDim.y) >> 3;
  int swz = (bid & 7) * cpx + (bid >> 3);
  int bx = swz % gridDim.x, by = swz / gridDim.x;
  int row0 = by * 128, col0 = bx * 64;

  floatx4 acc[4][2];
#pragma unroll
  for (int mt = 0; mt < 4; ++mt)
#pragma unroll
    for (int nt = 0; nt < 2; ++nt) acc[mt][nt] = (floatx4){0.f, 0.f, 0.f, 0.f};

  auto stageAB = [&](int buf, int k0) {
#pragma unroll
    for (int ch = 0; ch < 4; ++ch) {  // A: 1024 chunks, 4/thread
      int c = ch * 256 + tid;
      int r = c >> 3, g16 = c & 7;
      int sc = (g16 ^ (r & 7)) * 8;
      async_lds16(A + (size_t)(row0 + r) * K + k0 + sc,
                  &As[buf][(ch * 256 + wave * 64) * 8]);
    }
#pragma unroll
    for (int ch = 0; ch < 2; ++ch) {  // B: 512 chunks, 2/thread
      int c = ch * 256 + tid;
      int r = c >> 3, g16 = c & 7;
      int sc = (g16 ^ (r & 7)) * 8;
      async_lds16(BT + (size_t)(col0 + r) * K + k0 + sc,
                  &Bs[buf][(ch * 256 + wave * 64) * 8]);
    }
  };

  int niter = K >> 6;
  stageAB(0, 0);
  for (int i = 0; i < niter; ++i) {
    __builtin_amdgcn_s_barrier();  // all waves done reading buf (i+1)&1
    if (i + 1 < niter) {
      stageAB((i + 1) & 1, (i + 1) << 6);
      __builtin_amdgcn_s_waitcnt(WAIT_VM6);  // cur buffer's loads (prev iter) done
    } else {
      __builtin_amdgcn_s_waitcnt(WAIT_VM0);
    }
    __builtin_amdgcn_s_barrier();  // every wave's cur staging landed
    const bf16* Ac = As[i & 1];
    const bf16* Bc = Bs[i & 1];
    int sw = lm & 7;
#pragma unroll
    for (int ks = 0; ks < 64; ks += 32) {
      short8 af[4], bfr[2];
#pragma unroll
      for (int mt = 0; mt < 4; ++mt) {
        int R = wm * 64 + mt * 16 + lm;
        af[mt] = *(const short8*)&Ac[R * 64 + ((((ks >> 3) + quad) ^ sw) * 8)];
      }
#pragma unroll
      for (int nt = 0; nt < 2; ++nt) {
        int R = wn * 32 + nt * 16 + lm;
        bfr[nt] = *(const short8*)&Bc[R * 64 + ((((ks >> 3) + quad) ^ sw) * 8)];
      }
#pragma unroll
      for (int mt = 0; mt < 4; ++mt)
#pragma unroll
        for (int nt = 0; nt < 2; ++nt)
          acc[mt][nt] = MFMA16(af[mt], bfr[nt], acc[mt][nt]);
    }
  }
#pragma unroll
  for (int mt = 0; mt < 4; ++mt)
#pragma unroll
    for (int nt = 0; nt < 2; ++nt)
#pragma unroll
      for (int j = 0; j < 4; ++j) {
        int rr = row0 + wm * 64 + mt * 16 + quad * 4 + j;
        int cc = col0 + wn * 32 + nt * 16 + lm;
        storeC(C, (size_t)rr * N + cc, acc[mt][nt][j] * scale);
      }
}

// ------- flash attention: kv-SPLIT, 8 waves/block, dbuf 2-barrier -----------
// R13/R14: kv split across wave pairs (+6.3 µs, wave-starvation confirmed).
// R15: XCD-aware 1D grid swizzle. R14 FETCH=69.7 MB vs ~33 ideal: the 16
// qb-blocks sharing one (b,h)'s K/V (512 KB) round-robin'd across 8 XCDs —
// every XCD re-fetched K/V. Swizzle l=(p&7)*64+(p>>3) (bijective, 512%8==0)
// gives each XCD 4 complete (b,h) groups (2 MB K/V < 4 MB L2).
__global__ __launch_bounds__(512, 4) void attn_k(const bf16* __restrict__ Q,
                                                 const bf16* __restrict__ Km,
                                                 const bf16* __restrict__ VT,
                                                 const float* __restrict__ qB,
                                                 const float* __restrict__ kvB,
                                                 bf16* __restrict__ O) {
  const float TINY = 9.313225746154785e-10f;  // 2^-30
  __shared__ __align__(16) bf16 Ks[2][2][64 * 64];  // [stream][buf]
  __shared__ __align__(16) bf16 Vs[2][2][64 * 64];
  __shared__ __align__(16) float kvBs[2048];

  int tid = threadIdx.x;
  int wave = tid >> 6, lane = tid & 63;
  int quad = lane >> 4, lm = lane & 15;
  int strm = wave >> 2, sub = wave & 3;
  // XCD swizzle: physical p -> logical l; XCD p%8 owns 64 consecutive l
  int p = blockIdx.x;
  int l = (p & 7) * 64 + (p >> 3);
  int qb = l & 15, h = (l >> 4) & 15, b = l >> 8;
  int q0 = qb * 128 + sub * 32;

  const bf16* kbase = Km + (size_t)(b * 16 + h) * 2048 * 64;
  const bf16* vbase = VT + (size_t)(b * 16 + h) * 64 * 2048;
  const float* kvBb = kvB + b * 2048;

  // stage all 2048 kv biases to LDS (512 threads x 4 floats)
  {
    float4 v0 = *(const float4*)(kvBb + tid * 4);
    *(float4*)&kvBs[tid * 4] = v0;
  }

  short8 aq0[2], aq1[2];  // [qh]: Q B-frags for q-rows q0+qh*16+lm
  float qfac[2];
#pragma unroll
  for (int qh = 0; qh < 2; ++qh) {
    const bf16* qp = Q + (size_t)(b * 2048 + q0 + qh * 16 + lm) * 1024 + h * 64 + quad * 8;
    aq0[qh] = *(const short8*)qp;
    aq1[qh] = *(const short8*)(qp + 32);
    qfac[qh] = (qB[b * 2048 + q0 + qh * 16 + lm] == 0.0f) ? 1.0f : 0.0f;
  }

  floatx4 o_acc[2][4];
  floatx4 l_acc[2];
#pragma unroll
  for (int qh = 0; qh < 2; ++qh) {
    l_acc[qh] = (floatx4){0.f, 0.f, 0.f, 0.f};
#pragma unroll
    for (int t = 0; t < 4; ++t) o_acc[qh][t] = (floatx4){0.f, 0.f, 0.f, 0.f};
  }

  short8 ones;
#pragma unroll
  for (int i = 0; i < 8; ++i) ones[i] = (short)0x3F80;  // bf16 1.0

  union S8U { short8 s8; s16x4 h[2]; unsigned u[4]; };

  // wave stages its quarter of its stream's 64-kv tile (4 loads -> vmcnt(4))
  auto stageKV = [&](int buf, int it) {
    int kv0 = strm * 1024 + it * 64;
#pragma unroll
    for (int c = 0; c < 2; ++c) {
      int o = (sub * 2 + c) * 1024 + lane * 16;  // byte offset in 8KB tile
      int r = o >> 7;                             // tile row 0..63
      int g16 = (o >> 4) & 7;                     // 16B chunk in row
      int sc = ((g16 ^ (r & 7)) * 8);             // swizzled source elem col
      async_lds16(kbase + (size_t)(kv0 + r) * 64 + sc, &Ks[strm][buf][(sub * 2 + c) * 512]);
      async_lds16(vbase + (size_t)r * 2048 + kv0 + sc, &Vs[strm][buf][(sub * 2 + c) * 512]);
    }
  };

  __syncthreads();  // kvBs visible; drains Q/bias loads (vmcnt=0)
  stageKV(0, 0);
  for (int i = 0; i < 16; ++i) {
    int kv0 = strm * 1024 + i * 64;
    __builtin_amdgcn_s_barrier();  // all waves done reading buf (i+1)&1
    if (i + 1 < 16) {
      stageKV((i + 1) & 1, i + 1);
      __builtin_amdgcn_s_waitcnt(WAIT_VM4);  // cur buffer's loads (prev iter) done
    } else {
      __builtin_amdgcn_s_waitcnt(WAIT_VM0);
    }
    __builtin_amdgcn_s_barrier();  // every wave's cur staging landed
    const bf16* Kc = Ks[strm][i & 1];
    const bf16* Vc = Vs[strm][i & 1];

    // ---- S^T = K.Q^T per kv-tile t, both q-halves share the K frags ----
    S8U pf[2][2];  // [qh][kvhalf]
#pragma unroll
    for (int t = 0; t < 4; ++t) {
      int R = t * 16 + lm, sw = lm & 7;
      short8 kf0 = *(const short8*)&Kc[R * 64 + ((quad ^ sw) * 8)];
      short8 kf1 = *(const short8*)&Kc[R * 64 + (((quad + 4) ^ sw) * 8)];
      floatx4 zb = *(const floatx4*)&kvBs[kv0 + t * 16 + quad * 4];
      __builtin_amdgcn_s_setprio(1);
      floatx4 z0 = MFMA16(kf0, aq0[0], zb);
      z0 = MFMA16(kf1, aq1[0], z0);
      floatx4 z1 = MFMA16(kf0, aq0[1], zb);
      z1 = MFMA16(kf1, aq1[1], z1);
      __builtin_amdgcn_s_setprio(0);
      float p00 = fmaf(qfac[0], __builtin_amdgcn_exp2f(z0[0]), TINY);
      float p01 = fmaf(qfac[0], __builtin_amdgcn_exp2f(z0[1]), TINY);
      float p02 = fmaf(qfac[0], __builtin_amdgcn_exp2f(z0[2]), TINY);
      float p03 = fmaf(qfac[0], __builtin_amdgcn_exp2f(z0[3]), TINY);
      pf[0][t >> 1].u[(t & 1) * 2 + 0] = cvt_pk_bf16(p00, p01);
      pf[0][t >> 1].u[(t & 1) * 2 + 1] = cvt_pk_bf16(p02, p03);
      float p10 = fmaf(qfac[1], __builtin_amdgcn_exp2f(z1[0]), TINY);
      float p11 = fmaf(qfac[1], __builtin_amdgcn_exp2f(z1[1]), TINY);
      float p12 = fmaf(qfac[1], __builtin_amdgcn_exp2f(z1[2]), TINY);
      float p13 = fmaf(qfac[1], __builtin_amdgcn_exp2f(z1[3]), TINY);
      pf[1][t >> 1].u[(t & 1) * 2 + 0] = cvt_pk_bf16(p10, p11);
      pf[1][t >> 1].u[(t & 1) * 2 + 1] = cvt_pk_bf16(p12, p13);
    }
    // ---- O^T += V^T.P^T ; V frags shared by both q-halves ----
#pragma unroll
    for (int t = 0; t < 4; ++t) {
      int D = t * 16 + lm, sw = lm & 7;
      int hoff = (quad & 1) * 4, qh2 = quad >> 1;
      S8U vf0, vf1;
      vf0.h[0] = *(const s16x4*)&Vc[D * 64 + (((0 + qh2) ^ sw) * 8) + hoff];
      vf0.h[1] = *(const s16x4*)&Vc[D * 64 + (((2 + qh2) ^ sw) * 8) + hoff];
      vf1.h[0] = *(const s16x4*)&Vc[D * 64 + (((4 + qh2) ^ sw) * 8) + hoff];
      vf1.h[1] = *(const s16x4*)&Vc[D * 64 + (((6 + qh2) ^ sw) * 8) + hoff];
      __builtin_amdgcn_s_setprio(1);
      o_acc[0][t] = MFMA16(vf0.s8, pf[0][0].s8, o_acc[0][t]);
      o_acc[0][t] = MFMA16(vf1.s8, pf[0][1].s8, o_acc[0][t]);
      o_acc[1][t] = MFMA16(vf0.s8, pf[1][0].s8, o_acc[1][t]);
      o_acc[1][t] = MFMA16(vf1.s8, pf[1][1].s8, o_acc[1][t]);
      __builtin_amdgcn_s_setprio(0);
    }
    __builtin_amdgcn_s_setprio(1);
    l_acc[0] = MFMA16(ones, pf[0][0].s8, l_acc[0]);
    l_acc[0] = MFMA16(ones, pf[0][1].s8, l_acc[0]);
    l_acc[1] = MFMA16(ones, pf[1][0].s8, l_acc[1]);
    l_acc[1] = MFMA16(ones, pf[1][1].s8, l_acc[1]);
    __builtin_amdgcn_s_setprio(0);
  }

  // ---- epilogue: combine kv-halves via LDS (K/V buffers dead), write O ----
  __syncthreads();  // all waves done with K/V LDS + staging landed
  float* shO = (float*)&Ks[0][0][0];  // 32 KB: 256 rows x 32 floats
  float* shL = (float*)&Vs[0][0][0];  // 2 KB used
  int base = sub * 64 + lane;
  if (strm == 1) {
#pragma unroll
    for (int qh = 0; qh < 2; ++qh) {
#pragma unroll
      for (int t = 0; t < 4; ++t)
        *(floatx4*)&shO[(base * 8 + qh * 4 + t) * 4] = o_acc[qh][t];
      shL[base * 2 + qh] = l_acc[qh][0];
    }
  }
  __syncthreads();
  if (strm == 0) {
#pragma unroll
    for (int qh = 0; qh < 2; ++qh) {
      float l2 = l_acc[qh][0] + shL[base * 2 + qh];
      float rl = 1.0f / l2;
      bf16* orow = O + (size_t)(b * 2048 + q0 + qh * 16 + lm) * 1024 + h * 64;
#pragma unroll
      for (int t = 0; t < 4; ++t) {
        floatx4 pp = *(const floatx4*)&shO[(base * 8 + qh * 4 + t) * 4];
        floatx4 o = o_acc[qh][t] + pp;
        uint2 ov = {rne2(o[0] * rl, o[1] * rl), rne2(o[2] * rl, o[3] * rl)};
        *(uint2*)(orow + t * 16 + quad * 4) = ov;
      }
    }
  }
}

// ---------------- launch ----------------
extern "C" void kernel_launch(void* const* d_in, const int* in_sizes, int n_in,
                              void* d_out, int out_size, void* d_ws, size_t ws_size,
                              hipStream_t stream) {
  const float* x  = (const float*)d_in[0];   // [2,2048,1024] fp32
  const float* K  = (const float*)d_in[1];   // [2,16,2048,64] fp32
  const float* V  = (const float*)d_in[2];   // [2,16,2048,64] fp32
  const float* Wq = (const float*)d_in[3];   // [1024,1024] fp32
  const float* Wo = (const float*)d_in[4];   // [1024,1024] fp32
  const int* kvm  = (const int*)d_in[5];     // [2,1,1,2048] bool -> int32
  const int* qm   = (const int*)d_in[6];     // [2,1,2048,1] bool -> int32

  char* w = (char*)d_ws;
  bf16* xb    = (bf16*)(w);                        // 8 MB; reused as attnb (xb dead after gemm1)
  bf16* attnb = xb;
  bf16* Qb    = (bf16*)(w + (8u << 20));           // 8 MB (pre-scaled by log2e/sqrt(dk))
  bf16* Kb    = (bf16*)(w + (16u << 20));          // 8 MB
  bf16* VTb   = (bf16*)(w + (24u << 20));          // 8 MB [2,16,64,2048]
  bf16* WqT   = (bf16*)(w + (32u << 20));          // 2 MB
  bf16* WoT   = (bf16*)(w + (34u << 20));          // 2 MB
  float* qB   = (float*)(w + (36u << 20));         // 16 KB
  float* kvB  = (float*)(w + (36u << 20) + 16384); // 16 KB

  const float SCL2 = 0.18033688011112042f;  // log2(e)/sqrt(64)

  prep_k<<<9744, 256, 0, stream>>>(x, xb, K, Kb, Wq, WqT, Wo, WoT, V, VTb, kvm, qm, kvB, qB);
  gemm_bt_k<bf16><<<dim3(16, 32), 256, 0, stream>>>(xb, WqT, Qb, 4096, 1024, 1024, SCL2);
  attn_k<<<512, 512, 0, stream>>>(Qb, Kb, VTb, qB, kvB, attnb);
  gemm_bt_k<float><<<dim3(16, 32), 256, 0, stream>>>(attnb, WoT, (float*)d_out, 4096, 1024, 1024, 1.0f);
}

// Round 16
// 178.967 us; speedup vs baseline: 1.0482x; 1.0138x over previous
//
#include <hip/hip_runtime.h>
#include <hip/hip_bf16.h>
#include <stdint.h>

typedef __hip_bfloat16 bf16;
typedef __attribute__((ext_vector_type(8))) short short8;
typedef __attribute__((ext_vector_type(4))) short s16x4;
typedef __attribute__((ext_vector_type(4))) float floatx4;

#define MFMA16(a, b, c) __builtin_amdgcn_mfma_f32_16x16x32_bf16(a, b, c, 0, 0, 0)
// s_waitcnt imm: vmcnt[3:0], expcnt[6:4]=7 (no wait), lgkmcnt[11:8]=15 (no wait)
#define WAIT_VM6 3958  // 6 | (7<<4) | (15<<8)
#define WAIT_VM4 3956  // 4 | (7<<4) | (15<<8)
#define WAIT_VM0 3952  // 0 | (7<<4) | (15<<8)

__device__ __forceinline__ void async_lds16(const void* g, void* l) {
  __builtin_amdgcn_global_load_lds((__attribute__((address_space(1))) const void*)g,
                                   (__attribute__((address_space(3))) void*)l, 16, 0, 0);
}

// RNE-round two non-NaN floats to bf16, packed low|high into one u32
__device__ __forceinline__ unsigned rne2(float a, float b) {
  unsigned ua = __float_as_uint(a), ub = __float_as_uint(b);
  ua = ua + 0x7FFFu + ((ua >> 16) & 1u);
  ub = ub + 0x7FFFu + ((ub >> 16) & 1u);
  return (ua >> 16) | (ub & 0xFFFF0000u);
}

// single-instruction RNE pack (gfx950; no builtin — T12/m240). low16=a, high16=b
__device__ __forceinline__ unsigned cvt_pk_bf16(float a, float b) {
  unsigned r;
  asm("v_cvt_pk_bf16_f32 %0, %1, %2" : "=v"(r) : "v"(a), "v"(b));
  return r;
}

// ------------- fused prep: cvt(x,K) | transpose(Wq,Wo,V) | masks -------------
__global__ __launch_bounds__(256) void prep_k(const float* __restrict__ x, bf16* __restrict__ xb,
                                              const float* __restrict__ Kf, bf16* __restrict__ Kb,
                                              const float* __restrict__ Wq, bf16* __restrict__ WqT,
                                              const float* __restrict__ Wo, bf16* __restrict__ WoT,
                                              const float* __restrict__ V, bf16* __restrict__ VTb,
                                              const int* __restrict__ kvm, const int* __restrict__ qm,
                                              float* __restrict__ kvB, float* __restrict__ qB) {
  __shared__ float tile[64][65];
  int bid = blockIdx.x, tid = threadIdx.x;
  if (bid < 8192) {  // fp32 -> bf16 elementwise, 4 elems/thread
    const float* s; bf16* d; int g = bid;
    if (g < 4096) { s = x; d = xb; } else { s = Kf; d = Kb; g -= 4096; }
    int i = (g * 256 + tid) * 4;
    float4 v = *(const float4*)(s + i);
    uint2 o = {rne2(v.x, v.y), rne2(v.z, v.w)};
    *(uint2*)(d + i) = o;
    return;
  }
  if (bid < 9744 - 16) {  // 64x64 convert+transpose tiles
    const float* s; bf16* d; int r0, c0, R, C;
    if (bid < 8704) {
      int idx = bid - 8192;
      s = (idx >> 8) ? Wo : Wq; d = (idx >> 8) ? WoT : WqT;
      int rem = idx & 255;
      r0 = (rem & 15) * 64; c0 = (rem >> 4) * 64; R = 1024; C = 1024;
    } else {
      int idx = bid - 8704;
      int m = idx >> 5;
      s = V + (size_t)m * 2048 * 64; d = VTb + (size_t)m * 2048 * 64;
      r0 = (idx & 31) * 64; c0 = 0; R = 2048; C = 64;
    }
    int tr = tid >> 2, tg = tid & 3;
#pragma unroll
    for (int k = 0; k < 4; ++k) {
      int col = tg * 16 + k * 4;
      float4 v = *(const float4*)(s + (size_t)(r0 + tr) * C + c0 + col);
      tile[tr][col] = v.x; tile[tr][col + 1] = v.y;
      tile[tr][col + 2] = v.z; tile[tr][col + 3] = v.w;
    }
    __syncthreads();
    int orow = tid >> 2, ch = tid & 3;
    bf16* drow = d + (size_t)(c0 + orow) * R + r0;
    uint4 w0, w1;
    w0.x = rne2(tile[ch * 8 + 0][orow], tile[ch * 8 + 1][orow]);
    w0.y = rne2(tile[ch * 8 + 2][orow], tile[ch * 8 + 3][orow]);
    w0.z = rne2(tile[ch * 8 + 4][orow], tile[ch * 8 + 5][orow]);
    w0.w = rne2(tile[ch * 8 + 6][orow], tile[ch * 8 + 7][orow]);
    w1.x = rne2(tile[32 + ch * 8 + 0][orow], tile[32 + ch * 8 + 1][orow]);
    w1.y = rne2(tile[32 + ch * 8 + 2][orow], tile[32 + ch * 8 + 3][orow]);
    w1.z = rne2(tile[32 + ch * 8 + 4][orow], tile[32 + ch * 8 + 5][orow]);
    w1.w = rne2(tile[32 + ch * 8 + 6][orow], tile[32 + ch * 8 + 7][orow]);
    *(uint4*)(drow + ch * 8) = w0;
    *(uint4*)(drow + 32 + ch * 8) = w1;
    return;
  }
  int i = (bid - (9744 - 16)) * 256 + tid;  // mask -> additive log2 bias
  kvB[i] = kvm[i] ? 0.0f : -3000.0f;
  qB[i]  = qm[i]  ? 0.0f : -3000.0f;
}

// --- GEMM: C[M,N]=scale*(A @ BT^T), 128x64 tile, BK=64, 3-buf pipeline -----
// R16: residual arithmetic says GEMMs ~40-45 µs (~190 TF) and all three prior
// structures shared prefetch-depth-1 — latency-starved at 2 waves/SIMD.
// 3-buffer distance-2 prefetch, ONE barrier/iter (invariant structure = R12's
// correctness-clean attn 3-buf): stage(i) issued iter i-2; wave's vmcnt(6) in
// iter i-1 (after issuing stage(i+1): 12->6 outstanding) certifies stage(i);
// barrier at iter i publishes it + makes buf[(i+2)%3]=buf[(i-1)%3] WAR-safe
// (all waves finished compute(i-1)). LDS 72 KB -> still 2 blk/CU.
__device__ __forceinline__ void storeC(bf16* C, size_t i, float v) { C[i] = __float2bfloat16(v); }
__device__ __forceinline__ void storeC(float* C, size_t i, float v) { C[i] = v; }

template <typename OT>
__global__ __launch_bounds__(256, 2) void gemm_bt_k(const bf16* __restrict__ A,
                                                    const bf16* __restrict__ BT,
                                                    OT* __restrict__ C,
                                                    int M, int N, int K, float scale) {
  __shared__ __align__(16) bf16 As[3][128 * 64];
  __shared__ __align__(16) bf16 Bs[3][64 * 64];
  int tid = threadIdx.x;
  int wave = tid >> 6, lane = tid & 63;
  int quad = lane >> 4, lm = lane & 15;
  int wm = wave >> 1, wn = wave & 1;

  // bijective XCD swizzle: each XCD gets 64 consecutive logical tiles
  int bid = blockIdx.y * gridDim.x + blockIdx.x;
  int cpx = (gridDim.x * gridDim.y) >> 3;
  int swz = (bid & 7) * cpx + (bid >> 3);
  int bx = swz % gridDim.x, by = swz / gridDim.x;
  int row0 = by * 128, col0 = bx * 64;

  floatx4 acc[4][2];
#pragma unroll
  for (int mt = 0; mt < 4; ++mt)
#pragma unroll
    for (int nt = 0; nt < 2; ++nt) acc[mt][nt] = (floatx4){0.f, 0.f, 0.f, 0.f};

  auto stageAB = [&](int buf, int k0) {
#pragma unroll
    for (int ch = 0; ch < 4; ++ch) {  // A: 1024 chunks, 4/thread
      int c = ch * 256 + tid;
      int r = c >> 3, g16 = c & 7;
      int sc = (g16 ^ (r & 7)) * 8;
      async_lds16(A + (size_t)(row0 + r) * K + k0 + sc,
                  &As[buf][(ch * 256 + wave * 64) * 8]);
    }
#pragma unroll
    for (int ch = 0; ch < 2; ++ch) {  // B: 512 chunks, 2/thread
      int c = ch * 256 + tid;
      int r = c >> 3, g16 = c & 7;
      int sc = (g16 ^ (r & 7)) * 8;
      async_lds16(BT + (size_t)(col0 + r) * K + k0 + sc,
                  &Bs[buf][(ch * 256 + wave * 64) * 8]);
    }
  };

  int niter = K >> 6;
  stageAB(0, 0);
  stageAB(1, 64);
  __builtin_amdgcn_s_waitcnt(WAIT_VM6);  // own stage(0) landed (12 -> 6)
  __syncthreads();                        // publish tile 0 across waves
  int buf = 0;
  for (int i = 0; i < niter; ++i) {
    __builtin_amdgcn_s_barrier();  // publish stage(i); all compute(i-1) done
    if (i + 2 < niter) {
      stageAB(buf == 0 ? 2 : buf - 1, (i + 2) << 6);  // (i+2)%3
      __builtin_amdgcn_s_waitcnt(WAIT_VM6);           // certify stage(i+1)
    } else {
      __builtin_amdgcn_s_waitcnt(WAIT_VM0);           // drain final tiles
    }
    const bf16* Ac = As[buf];
    const bf16* Bc = Bs[buf];
    int sw = lm & 7;
#pragma unroll
    for (int ks = 0; ks < 64; ks += 32) {
      short8 af[4], bfr[2];
#pragma unroll
      for (int mt = 0; mt < 4; ++mt) {
        int R = wm * 64 + mt * 16 + lm;
        af[mt] = *(const short8*)&Ac[R * 64 + ((((ks >> 3) + quad) ^ sw) * 8)];
      }
#pragma unroll
      for (int nt = 0; nt < 2; ++nt) {
        int R = wn * 32 + nt * 16 + lm;
        bfr[nt] = *(const short8*)&Bc[R * 64 + ((((ks >> 3) + quad) ^ sw) * 8)];
      }
#pragma unroll
      for (int mt = 0; mt < 4; ++mt)
#pragma unroll
        for (int nt = 0; nt < 2; ++nt)
          acc[mt][nt] = MFMA16(af[mt], bfr[nt], acc[mt][nt]);
    }
    buf = (buf == 2) ? 0 : buf + 1;
  }
#pragma unroll
  for (int mt = 0; mt < 4; ++mt)
#pragma unroll
    for (int nt = 0; nt < 2; ++nt)
#pragma unroll
      for (int j = 0; j < 4; ++j) {
        int rr = row0 + wm * 64 + mt * 16 + quad * 4 + j;
        int cc = col0 + wn * 32 + nt * 16 + lm;
        storeC(C, (size_t)rr * N + cc, acc[mt][nt][j] * scale);
      }
}

// ------- flash attention: kv-SPLIT, 8 waves/block, dbuf 2-barrier -----------
// R13/R14: kv split across wave pairs (+6.3 µs, wave-starvation confirmed).
// R15: XCD swizzle — FETCH 69.7->12.4 MB confirmed, time null => attn is
// latency-bound and structurally parked at ~49.6 µs at this decomposition.
__global__ __launch_bounds__(512, 4) void attn_k(const bf16* __restrict__ Q,
                                                 const bf16* __restrict__ Km,
                                                 const bf16* __restrict__ VT,
                                                 const float* __restrict__ qB,
                                                 const float* __restrict__ kvB,
                                                 bf16* __restrict__ O) {
  const float TINY = 9.313225746154785e-10f;  // 2^-30
  __shared__ __align__(16) bf16 Ks[2][2][64 * 64];  // [stream][buf]
  __shared__ __align__(16) bf16 Vs[2][2][64 * 64];
  __shared__ __align__(16) float kvBs[2048];

  int tid = threadIdx.x;
  int wave = tid >> 6, lane = tid & 63;
  int quad = lane >> 4, lm = lane & 15;
  int strm = wave >> 2, sub = wave & 3;
  // XCD swizzle: physical p -> logical l; XCD p%8 owns 64 consecutive l
  int p = blockIdx.x;
  int l = (p & 7) * 64 + (p >> 3);
  int qb = l & 15, h = (l >> 4) & 15, b = l >> 8;
  int q0 = qb * 128 + sub * 32;

  const bf16* kbase = Km + (size_t)(b * 16 + h) * 2048 * 64;
  const bf16* vbase = VT + (size_t)(b * 16 + h) * 64 * 2048;
  const float* kvBb = kvB + b * 2048;

  // stage all 2048 kv biases to LDS (512 threads x 4 floats)
  {
    float4 v0 = *(const float4*)(kvBb + tid * 4);
    *(float4*)&kvBs[tid * 4] = v0;
  }

  short8 aq0[2], aq1[2];  // [qh]: Q B-frags for q-rows q0+qh*16+lm
  float qfac[2];
#pragma unroll
  for (int qh = 0; qh < 2; ++qh) {
    const bf16* qp = Q + (size_t)(b * 2048 + q0 + qh * 16 + lm) * 1024 + h * 64 + quad * 8;
    aq0[qh] = *(const short8*)qp;
    aq1[qh] = *(const short8*)(qp + 32);
    qfac[qh] = (qB[b * 2048 + q0 + qh * 16 + lm] == 0.0f) ? 1.0f : 0.0f;
  }

  floatx4 o_acc[2][4];
  floatx4 l_acc[2];
#pragma unroll
  for (int qh = 0; qh < 2; ++qh) {
    l_acc[qh] = (floatx4){0.f, 0.f, 0.f, 0.f};
#pragma unroll
    for (int t = 0; t < 4; ++t) o_acc[qh][t] = (floatx4){0.f, 0.f, 0.f, 0.f};
  }

  short8 ones;
#pragma unroll
  for (int i = 0; i < 8; ++i) ones[i] = (short)0x3F80;  // bf16 1.0

  union S8U { short8 s8; s16x4 h[2]; unsigned u[4]; };

  // wave stages its quarter of its stream's 64-kv tile (4 loads -> vmcnt(4))
  auto stageKV = [&](int buf, int it) {
    int kv0 = strm * 1024 + it * 64;
#pragma unroll
    for (int c = 0; c < 2; ++c) {
      int o = (sub * 2 + c) * 1024 + lane * 16;  // byte offset in 8KB tile
      int r = o >> 7;                             // tile row 0..63
      int g16 = (o >> 4) & 7;                     // 16B chunk in row
      int sc = ((g16 ^ (r & 7)) * 8);             // swizzled source elem col
      async_lds16(kbase + (size_t)(kv0 + r) * 64 + sc, &Ks[strm][buf][(sub * 2 + c) * 512]);
      async_lds16(vbase + (size_t)r * 2048 + kv0 + sc, &Vs[strm][buf][(sub * 2 + c) * 512]);
    }
  };

  __syncthreads();  // kvBs visible; drains Q/bias loads (vmcnt=0)
  stageKV(0, 0);
  for (int i = 0; i < 16; ++i) {
    int kv0 = strm * 1024 + i * 64;
    __builtin_amdgcn_s_barrier();  // all waves done reading buf (i+1)&1
    if (i + 1 < 16) {
      stageKV((i + 1) & 1, i + 1);
      __builtin_amdgcn_s_waitcnt(WAIT_VM4);  // cur buffer's loads (prev iter) done
    } else {
      __builtin_amdgcn_s_waitcnt(WAIT_VM0);
    }
    __builtin_amdgcn_s_barrier();  // every wave's cur staging landed
    const bf16* Kc = Ks[strm][i & 1];
    const bf16* Vc = Vs[strm][i & 1];

    // ---- S^T = K.Q^T per kv-tile t, both q-halves share the K frags ----
    S8U pf[2][2];  // [qh][kvhalf]
#pragma unroll
    for (int t = 0; t < 4; ++t) {
      int R = t * 16 + lm, sw = lm & 7;
      short8 kf0 = *(const short8*)&Kc[R * 64 + ((quad ^ sw) * 8)];
      short8 kf1 = *(const short8*)&Kc[R * 64 + (((quad + 4) ^ sw) * 8)];
      floatx4 zb = *(const floatx4*)&kvBs[kv0 + t * 16 + quad * 4];
      __builtin_amdgcn_s_setprio(1);
      floatx4 z0 = MFMA16(kf0, aq0[0], zb);
      z0 = MFMA16(kf1, aq1[0], z0);
      floatx4 z1 = MFMA16(kf0, aq0[1], zb);
      z1 = MFMA16(kf1, aq1[1], z1);
      __builtin_amdgcn_s_setprio(0);
      float p00 = fmaf(qfac[0], __builtin_amdgcn_exp2f(z0[0]), TINY);
      float p01 = fmaf(qfac[0], __builtin_amdgcn_exp2f(z0[1]), TINY);
      float p02 = fmaf(qfac[0], __builtin_amdgcn_exp2f(z0[2]), TINY);
      float p03 = fmaf(qfac[0], __builtin_amdgcn_exp2f(z0[3]), TINY);
      pf[0][t >> 1].u[(t & 1) * 2 + 0] = cvt_pk_bf16(p00, p01);
      pf[0][t >> 1].u[(t & 1) * 2 + 1] = cvt_pk_bf16(p02, p03);
      float p10 = fmaf(qfac[1], __builtin_amdgcn_exp2f(z1[0]), TINY);
      float p11 = fmaf(qfac[1], __builtin_amdgcn_exp2f(z1[1]), TINY);
      float p12 = fmaf(qfac[1], __builtin_amdgcn_exp2f(z1[2]), TINY);
      float p13 = fmaf(qfac[1], __builtin_amdgcn_exp2f(z1[3]), TINY);
      pf[1][t >> 1].u[(t & 1) * 2 + 0] = cvt_pk_bf16(p10, p11);
      pf[1][t >> 1].u[(t & 1) * 2 + 1] = cvt_pk_bf16(p12, p13);
    }
    // ---- O^T += V^T.P^T ; V frags shared by both q-halves ----
#pragma unroll
    for (int t = 0; t < 4; ++t) {
      int D = t * 16 + lm, sw = lm & 7;
      int hoff = (quad & 1) * 4, qh2 = quad >> 1;
      S8U vf0, vf1;
      vf0.h[0] = *(const s16x4*)&Vc[D * 64 + (((0 + qh2) ^ sw) * 8) + hoff];
      vf0.h[1] = *(const s16x4*)&Vc[D * 64 + (((2 + qh2) ^ sw) * 8) + hoff];
      vf1.h[0] = *(const s16x4*)&Vc[D * 64 + (((4 + qh2) ^ sw) * 8) + hoff];
      vf1.h[1] = *(const s16x4*)&Vc[D * 64 + (((6 + qh2) ^ sw) * 8) + hoff];
      __builtin_amdgcn_s_setprio(1);
      o_acc[0][t] = MFMA16(vf0.s8, pf[0][0].s8, o_acc[0][t]);
      o_acc[0][t] = MFMA16(vf1.s8, pf[0][1].s8, o_acc[0][t]);
      o_acc[1][t] = MFMA16(vf0.s8, pf[1][0].s8, o_acc[1][t]);
      o_acc[1][t] = MFMA16(vf1.s8, pf[1][1].s8, o_acc[1][t]);
      __builtin_amdgcn_s_setprio(0);
    }
    __builtin_amdgcn_s_setprio(1);
    l_acc[0] = MFMA16(ones, pf[0][0].s8, l_acc[0]);
    l_acc[0] = MFMA16(ones, pf[0][1].s8, l_acc[0]);
    l_acc[1] = MFMA16(ones, pf[1][0].s8, l_acc[1]);
    l_acc[1] = MFMA16(ones, pf[1][1].s8, l_acc[1]);
    __builtin_amdgcn_s_setprio(0);
  }

  // ---- epilogue: combine kv-halves via LDS (K/V buffers dead), write O ----
  __syncthreads();  // all waves done with K/V LDS + staging landed
  float* shO = (float*)&Ks[0][0][0];  // 32 KB: 256 rows x 32 floats
  float* shL = (float*)&Vs[0][0][0];  // 2 KB used
  int base = sub * 64 + lane;
  if (strm == 1) {
#pragma unroll
    for (int qh = 0; qh < 2; ++qh) {
#pragma unroll
      for (int t = 0; t < 4; ++t)
        *(floatx4*)&shO[(base * 8 + qh * 4 + t) * 4] = o_acc[qh][t];
      shL[base * 2 + qh] = l_acc[qh][0];
    }
  }
  __syncthreads();
  if (strm == 0) {
#pragma unroll
    for (int qh = 0; qh < 2; ++qh) {
      float l2 = l_acc[qh][0] + shL[base * 2 + qh];
      float rl = 1.0f / l2;
      bf16* orow = O + (size_t)(b * 2048 + q0 + qh * 16 + lm) * 1024 + h * 64;
#pragma unroll
      for (int t = 0; t < 4; ++t) {
        floatx4 pp = *(const floatx4*)&shO[(base * 8 + qh * 4 + t) * 4];
        floatx4 o = o_acc[qh][t] + pp;
        uint2 ov = {rne2(o[0] * rl, o[1] * rl), rne2(o[2] * rl, o[3] * rl)};
        *(uint2*)(orow + t * 16 + quad * 4) = ov;
      }
    }
  }
}

// ---------------- launch ----------------
extern "C" void kernel_launch(void* const* d_in, const int* in_sizes, int n_in,
                              void* d_out, int out_size, void* d_ws, size_t ws_size,
                              hipStream_t stream) {
  const float* x  = (const float*)d_in[0];   // [2,2048,1024] fp32
  const float* K  = (const float*)d_in[1];   // [2,16,2048,64] fp32
  const float* V  = (const float*)d_in[2];   // [2,16,2048,64] fp32
  const float* Wq = (const float*)d_in[3];   // [1024,1024] fp32
  const float* Wo = (const float*)d_in[4];   // [1024,1024] fp32
  const int* kvm  = (const int*)d_in[5];     // [2,1,1,2048] bool -> int32
  const int* qm   = (const int*)d_in[6];     // [2,1,2048,1] bool -> int32

  char* w = (char*)d_ws;
  bf16* xb    = (bf16*)(w);                        // 8 MB; reused as attnb (xb dead after gemm1)
  bf16* attnb = xb;
  bf16* Qb    = (bf16*)(w + (8u << 20));           // 8 MB (pre-scaled by log2e/sqrt(dk))
  bf16* Kb    = (bf16*)(w + (16u << 20));          // 8 MB
  bf16* VTb   = (bf16*)(w + (24u << 20));          // 8 MB [2,16,64,2048]
  bf16* WqT   = (bf16*)(w + (32u << 20));          // 2 MB
  bf16* WoT   = (bf16*)(w + (34u << 20));          // 2 MB
  float* qB   = (float*)(w + (36u << 20));         // 16 KB
  float* kvB  = (float*)(w + (36u << 20) + 16384); // 16 KB

  const float SCL2 = 0.18033688011112042f;  // log2(e)/sqrt(64)

  prep_k<<<9744, 256, 0, stream>>>(x, xb, K, Kb, Wq, WqT, Wo, WoT, V, VTb, kvm, qm, kvB, qB);
  gemm_bt_k<bf16><<<dim3(16, 32), 256, 0, stream>>>(xb, WqT, Qb, 4096, 1024, 1024, SCL2);
  attn_k<<<512, 512, 0, stream>>>(Qb, Kb, VTb, qB, kvB, attnb);
  gemm_bt_k<float><<<dim3(16, 32), 256, 0, stream>>>(attnb, WoT, (float*)d_out, 4096, 1024, 1024, 1.0f);
}